// Round 1
// baseline (106.207 us; speedup 1.0000x reference)
//
#include <hip/hip_runtime.h>

// SIR recurrence: 2047 strictly-sequential steps of a 4-state quadratic map.
// One lane runs the recurrence (dep-chain-bound: 3 dependent FMAs/step);
// threads 1..255 zero column 4 of the output in parallel.
//
// Algebraic pre-fold (vs. reference op order, <= ~2ulp/step, contracting):
//   a = w2*(w2*u)            -> w2sq*u            (feeds s1, u')
//   b = w4*(w4*u)            -> w4sq*u            (feeds s3, u')
//   c = w3*(w3*(u/1000*v)+b3)+b3 -> fma(gamma, u*v, delta)
//        gamma = w3*w3/1000, delta = w3*b3+b3
//   u' = u - a - b + c       -> fma(L, u, c), L = 1 - w2sq - w4sq

__global__ __launch_bounds__(256) void sir_kernel(
    const float* __restrict__ x, const float* __restrict__ w2p,
    const float* __restrict__ w3p, const float* __restrict__ b3p,
    const float* __restrict__ w4p, const int* __restrict__ np,
    float* __restrict__ out) {
  const int n = *np;
  const int rows = n - 1;  // 2047 output rows: states ns[1]..ns[n-1]
  const int tid = threadIdx.x;

  if (tid != 0) {
    // Column 4 is 0 for every output row (torch module never writes slot 4).
    // d_out is re-poisoned to 0xAA before every launch, so write it.
    for (int i = tid - 1; i < rows; i += 255) out[5 * i + 4] = 0.0f;
    return;
  }

  const float w2 = *w2p, w3 = *w3p, b3 = *b3p, w4 = *w4p;
  const float w2sq  = w2 * w2;
  const float w4sq  = w4 * w4;
  const float L     = 1.0f - w2sq - w4sq;
  const float gamma = (w3 * w3) / 1000.0f;
  const float delta = fmaf(w3, b3, b3);

  float u  = x[0];  // s0
  float s1 = x[1];
  float v  = x[2];  // s2
  float s3 = x[3];

  float* p = out;
#pragma unroll 4
  for (int i = 0; i < rows; ++i) {
    // critical path: t -> c -> {u', v'}  (3 dependent VALU ops)
    const float t  = u * v;
    const float c  = fmaf(gamma, t, delta);
    const float nu = fmaf(L, u, c);
    const float nv = v - c;
    // off critical path
    s1 = fmaf(w2sq, u, s1);
    s3 = fmaf(w4sq, u, s3);
    u = nu;
    v = nv;
    p[0] = nu;
    p[1] = s1;
    p[2] = nv;
    p[3] = s3;
    p += 5;
  }
}

extern "C" void kernel_launch(void* const* d_in, const int* in_sizes, int n_in,
                              void* d_out, int out_size, void* d_ws, size_t ws_size,
                              hipStream_t stream) {
  const float* x   = (const float*)d_in[0];
  const float* w2  = (const float*)d_in[1];
  const float* w3  = (const float*)d_in[2];
  const float* b3  = (const float*)d_in[3];
  const float* w4  = (const float*)d_in[4];
  const int*   n   = (const int*)d_in[5];
  float* out = (float*)d_out;
  sir_kernel<<<1, 256, 0, stream>>>(x, w2, w3, b3, w4, n, out);
}